// Round 8
// baseline (256.030 us; speedup 1.0000x reference)
//
#include <hip/hip_runtime.h>
#include <stdint.h>

#define B_ 4
#define T_ 2048
#define C_ 1024
#define H_ 16
#define D_ 64
#define M_ (B_*T_)      /* 8192 */
#define K_ C_           /* 1024 */

typedef unsigned short ushort_t;
typedef __bf16 bf16x8 __attribute__((ext_vector_type(8)));
typedef float  float4_ __attribute__((ext_vector_type(4)));
typedef ushort_t ushort4_ __attribute__((ext_vector_type(4)));
typedef uint32_t uint32x2 __attribute__((ext_vector_type(2)));

__device__ __forceinline__ ushort_t f2bf(float f) {
    union { float f; uint32_t u; } c; c.f = f;
    uint32_t u = c.u;
    uint32_t r = (u + 0x7FFFu + ((u >> 16) & 1u)) >> 16;
    return (ushort_t)r;
}
__device__ __forceinline__ float4_ f4zero() { float4_ z; z[0]=0.f; z[1]=0.f; z[2]=0.f; z[3]=0.f; return z; }

// packed f32x2 -> bf16x2 (single HW instr; no builtin on gfx950 — T12 recipe)
__device__ __forceinline__ uint32_t cvtpk(float a, float b) {
    uint32_t r;
    asm("v_cvt_pk_bf16_f32 %0, %1, %2" : "=v"(r) : "v"(a), "v"(b));
    return r;
}

// async global->LDS, 16B per lane; LDS dest must be wave-uniform base + lane*16
#define GLDS16(gptr, lptr) \
    __builtin_amdgcn_global_load_lds((const __attribute__((address_space(1))) uint32_t*)(gptr), \
                                     (__attribute__((address_space(3))) uint32_t*)(lptr), 16, 0, 0)

// ---------------------------------------------------------------------------
// fused input prep (one launch; r7 had two):
//   blocks     0.. 8191:  x f32 [8M elems] -> x_bf bf16
//   blocks  8192..11263:  wq|wk|wv f32 -> wcat bf16 [3072][1024]
//   blocks 11264..11519:  w_o f32 [1024(hd)][1024(c)] -> wot bf16 [1024(c)][1024(hd)]
// ---------------------------------------------------------------------------
__global__ __launch_bounds__(256) void prep_all(const float* __restrict__ x,
                                                ushort_t* __restrict__ x_bf,
                                                const float* __restrict__ s0,
                                                const float* __restrict__ s1,
                                                const float* __restrict__ s2,
                                                ushort_t* __restrict__ dst,
                                                const float* __restrict__ wo,
                                                ushort_t* __restrict__ wot) {
    __shared__ ushort_t tile[64][65];
    const int b = blockIdx.x;
    const int tid = threadIdx.x;
    if (b < 8192) {
        const int i = b * 1024 + tid * 4;
        float4_ v = *(const float4_*)(x + i);
        ushort4_ o;
        #pragma unroll
        for (int e = 0; e < 4; e++) o[e] = f2bf(v[e]);
        *(ushort4_*)(x_bf + i) = o;
    } else if (b < 11264) {
        const int bw = b - 8192;                 // 0..3071
        const float* src = (bw < 1024) ? s0 : (bw < 2048) ? s1 : s2;
        const int off = (bw & 1023) * 1024 + tid * 4;
        float4_ v = *(const float4_*)(src + off);
        ushort4_ o;
        #pragma unroll
        for (int e = 0; e < 4; e++) o[e] = f2bf(v[e]);
        *(ushort4_*)(dst + (size_t)bw * 1024 + tid * 4) = o;
    } else {
        const int bb = b - 11264;                // 0..255
        const int c0 = (bb & 15) * 64;
        const int r0 = (bb >> 4) * 64;           // hd tile base
        const int row = tid >> 2;                // 64 rows, 4 threads/row
        const int col = (tid & 3) * 16;
        #pragma unroll
        for (int r = 0; r < 4; r++) {
            float4_ v = *(const float4_*)(wo + (size_t)(r0 + row) * 1024 + c0 + col + r * 4);
            #pragma unroll
            for (int e = 0; e < 4; e++) tile[row][col + r * 4 + e] = f2bf(v[e]);
        }
        __syncthreads();
        #pragma unroll
        for (int r = 0; r < 2; r++) {
            bf16x8 v;
            #pragma unroll
            for (int e = 0; e < 8; e++) v[e] = __builtin_bit_cast(__bf16, tile[col + r * 8 + e][row]);
            *(bf16x8*)(wot + (size_t)(c0 + row) * 1024 + r0 + col + r * 8) = v;
        }
    }
}

// ---------------------------------------------------------------------------
// GEMM: C[M x N] = A[M x K] * Bt[N x K]^T  (bf16 in, fp32 acc)
// PROVEN r3 structure (82 us @ MODE 0 after r7 packed-V^T epilogue):
// 128x128 tile, 2-barrier K-loop, global_load_lds width=16 staging.
// ROUND 8: XCD-chunked block swizzle. Counters show 6% of staged lines miss
//   L2 (FETCH 49 MB vs 786 MB staged) and that miss latency lands inside the
//   per-K-step vmcnt(0)+barrier drain. Round-robin XCD dispatch gives every
//   private 4 MB L2 the full 6 MB B working set (24 n-panels) -> thrash.
//   Chunked remap: each XCD owns NB/8 consecutive flat ids = 3 (MODE0) / 1
//   (MODE1) contiguous by-panels; B stays L2-resident, A streams.
//   Bijective since NB % 8 == 0 (1536 / 512).
// MODE 0: Bt = Wcat [3072 x 1024]; scatters Q (x 0.125*log2(e), exp2-domain
//         softmax), K [nh][t][d], V^T [nh][d][t] (packed ushort4_ stores)
// MODE 1: Bt = wot [1024 x 1024]; f32 store to d_out
// ---------------------------------------------------------------------------
template<int MODE>
__global__ __launch_bounds__(256, 4)
void gemm_bt(const ushort_t* __restrict__ A,
             const ushort_t* __restrict__ Bt,
             ushort_t* __restrict__ q_ws, ushort_t* __restrict__ k_ws,
             ushort_t* __restrict__ vt_ws, float* __restrict__ outp)
{
    __shared__ __align__(16) ushort_t As[128 * 32];
    __shared__ __align__(16) ushort_t Bs[128 * 32];
    const int tid = threadIdx.x;
    // XCD-chunked swizzle: flat id -> (bx, by) so each XCD gets contiguous
    // by-panels (B L2-residency). NB = 1536 (MODE0) / 512 (MODE1), both %8==0.
    const int NB   = gridDim.x * gridDim.y;
    const int flat = blockIdx.y * gridDim.x + blockIdx.x;
    const int fl2  = (flat & 7) * (NB >> 3) + (flat >> 3);
    const int m0 = (fl2 & 63) * 128;
    const int n0 = (fl2 >> 6) * 128;

    const int L    = tid & 63;
    const int wid  = tid >> 6;
    const int wr   = (wid >> 1) * 64;
    const int wc   = (wid & 1) * 64;
    const int quad = L >> 4;
    const int lc   = L & 15;

    float4_ acc[4][4];
    #pragma unroll
    for (int i = 0; i < 4; i++)
        #pragma unroll
        for (int j = 0; j < 4; j++) acc[i][j] = f4zero();

    const int loff0 = wid * 1024 + L * 16;   // per-lane byte offset = wave-base + lane*16
    for (int k0 = 0; k0 < K_; k0 += 32) {
        __syncthreads();
        #pragma unroll
        for (int r = 0; r < 2; r++) {
            const int off = loff0 + r * 4096;
            const int row = off >> 6;    // 64 B per tile row (32 bf16)
            const int col = off & 63;    // byte col
            const char* ga = (const char*)A  + (size_t)(m0 + row) * (K_ * 2) + k0 * 2 + col;
            const char* gb = (const char*)Bt + (size_t)(n0 + row) * (K_ * 2) + k0 * 2 + col;
            GLDS16(ga, (char*)As + off);
            GLDS16(gb, (char*)Bs + off);
        }
        __syncthreads();
        bf16x8 af[4], bfr[4];
        #pragma unroll
        for (int i = 0; i < 4; i++) {
            const int m = wr + i * 16 + lc;
            af[i]  = *(const bf16x8*)((const char*)As + m * 64 + quad * 16);
            const int n = wc + i * 16 + lc;
            bfr[i] = *(const bf16x8*)((const char*)Bs + n * 64 + quad * 16);
        }
        #pragma unroll
        for (int i = 0; i < 4; i++)
            #pragma unroll
            for (int j = 0; j < 4; j++)
                acc[i][j] = __builtin_amdgcn_mfma_f32_16x16x32_bf16(af[i], bfr[j], acc[i][j], 0, 0, 0);
    }

    // epilogue: C/D layout col=lane&15, row=quad*4+reg (m89-verified)
    const int mat = n0 >> 10;          // MODE 0: which of q/k/v
    const int nb  = n0 & 1023;
    if (MODE == 1) {
        #pragma unroll
        for (int i = 0; i < 4; i++)
            #pragma unroll
            for (int j = 0; j < 4; j++)
                #pragma unroll
                for (int rg = 0; rg < 4; rg++) {
                    const int mg = m0 + wr + i * 16 + quad * 4 + rg;
                    const int cg = n0 + wc + j * 16 + lc;
                    outp[(size_t)mg * 1024 + cg] = acc[i][j][rg];     // f32 store
                }
    } else if (mat == 2) {
        // V^T [nh][d][t]: rg values are t-consecutive -> one ushort4_ per (i,j)
        #pragma unroll
        for (int i = 0; i < 4; i++) {
            const int mg0 = m0 + wr + i * 16 + quad * 4;
            const int n = mg0 >> 11, t0 = mg0 & 2047;
            #pragma unroll
            for (int j = 0; j < 4; j++) {
                const int ln = nb + wc + j * 16 + lc;
                const int h = ln >> 6, d = ln & 63;
                const int nh = n * H_ + h;
                ushort4_ pk;
                #pragma unroll
                for (int rg = 0; rg < 4; rg++) pk[rg] = f2bf(acc[i][j][rg]);
                *(ushort4_*)(vt_ws + ((size_t)nh * 64 + d) * T_ + t0) = pk;
            }
        }
    } else {
        // Q (x 0.125*log2(e): softmax computed with exp2) or K, [nh][t][d]
        const float scl = (mat == 0) ? 0.18033688011112042f : 1.0f;
        ushort_t* dstp  = (mat == 0) ? q_ws : k_ws;
        #pragma unroll
        for (int i = 0; i < 4; i++)
            #pragma unroll
            for (int j = 0; j < 4; j++)
                #pragma unroll
                for (int rg = 0; rg < 4; rg++) {
                    const int mg = m0 + wr + i * 16 + quad * 4 + rg;
                    const int ln = nb + wc + j * 16 + lc;
                    const int h = ln >> 6, d = ln & 63;
                    const int n = mg >> 11, t = mg & 2047;
                    const int nh = n * H_ + h;
                    dstp[((size_t)nh * T_ + t) * 64 + d] = f2bf(acc[i][j][rg] * scl);
                }
    }
}

// ---------------------------------------------------------------------------
// MFMA flash attention, transposed formulation (round-3, validated):
//   S^T = K Q^T ; O^T = V^T P^T ; per-lane scalar softmax state (exp2 domain).
//   Global heavy-first dispatch + XCD-local nh mapping.
// ---------------------------------------------------------------------------
#define KP 72   /* Ps padded row pitch, elements (P path only) */

__global__ __launch_bounds__(512)
void attn(const ushort_t* __restrict__ q_ws, const ushort_t* __restrict__ k_ws,
          const ushort_t* __restrict__ vt_ws, ushort_t* __restrict__ y_ws)
{
    __shared__ __align__(16) ushort_t Ks[2][64 * 64];   // [s][d] 128B pitch, swizzled
    __shared__ __align__(16) ushort_t Vs[2][64 * 64];   // [d][s] 128B pitch, swizzled
    __shared__ __align__(16) ushort_t Ps[8][16 * KP];   // per-wave P^T as [t][s]
    const int tid  = threadIdx.x;
    const int L    = tid & 63;
    const int w    = tid >> 6;           // 0..7
    const int quad = L >> 4, lc = L & 15;
    const int bid  = blockIdx.x;
    const int qt   = 15 - (bid >> 6);    // GLOBAL heavy-first: qt=15 blocks first
    const int nh   = bid & 63;           // bid%8 == nh%8 -> XCD-local K/V
    const int n    = nh >> 4;
    const int tq0  = qt * 128 + w * 16;
    const int tg   = tq0 + lc;           // this lane's q-row
    const int nt   = 2 * qt + 2;         // K/V 64-tiles this block touches
    const int dstile = tq0 >> 6;         // first tile needing the causal mask

    // Q fragments (B-operand layout [n=t=lc][k=d=quad*8+j]):
    const ushort_t* qbase = q_ws + ((size_t)nh * T_ + tq0) * 64;
    const bf16x8 qf0 = *(const bf16x8*)(qbase + (size_t)lc * 64 + quad * 8);
    const bf16x8 qf1 = *(const bf16x8*)(qbase + (size_t)lc * 64 + quad * 8 + 32);

    float m_i = -1e30f, l_i = 0.f;       // per-lane scalars (q-row tg), log2 domain
    float4_ o[4];                        // O^T C-layout: col=t (lane), row=d
    #pragma unroll
    for (int r = 0; r < 4; r++) o[r] = f4zero();

    const char* kbase = (const char*)(k_ws  + (size_t)nh * T_ * 64);   // [t][d]
    const char* vbase = (const char*)(vt_ws + (size_t)nh * 64 * T_);   // [d][t]
    char* pwr = (char*)Ps[w] + lc * (KP * 2);

    // staging: 512 threads x 16B = one 8KB tile per glds instruction.
    const int ldsoff = tid * 16;                 // linear byte offset in 8KB buffer
    const int srow   = ldsoff >> 7;              // 0..63
    const int sslot  = (ldsoff >> 4) & 7;
    const int sgs    = sslot ^ (srow & 7);       // inverse swizzle on SOURCE
    const size_t kgo = (size_t)srow * 128 + sgs * 16;
    const size_t vgo = (size_t)srow * (T_ * 2) + sgs * 16;

    // loop-invariant swizzled read offsets (rows b*16+lc, 16B slots quad/quad+4)
    int off16[4][2];
    #pragma unroll
    for (int b = 0; b < 4; b++) {
        const int row = b * 16 + lc;
        const int r7  = lc & 7;                  // (b*16+lc)&7 == lc&7
        off16[b][0] = row * 128 + ((quad ^ r7) << 4);
        off16[b][1] = row * 128 + (((quad + 4) ^ r7) << 4);
    }

    auto STAGE = [&](int st, int b) {
        GLDS16(kbase + (size_t)st * 8192 + kgo, (char*)Ks[b] + ldsoff);
        GLDS16(vbase + (size_t)st * 128  + vgo, (char*)Vs[b] + ldsoff);
    };

    STAGE(0, 0);
    __syncthreads();                      // drains vmcnt(0): buf0 staged
    int cur = 0;

    for (int st = 0; st < nt; st++) {
        if (st + 1 < nt) STAGE(st + 1, cur ^ 1);   // prefetch overlaps compute
        // wave-uniform skip of fully-masked final tile (lower-half waves)
        if (st * 64 <= tq0 + 15) {
            const char* ks = (const char*)Ks[cur];
            const char* vs = (const char*)Vs[cur];

            // S^T = K Q^T: 4 s-blocks of 16; D[s][t]: row=quad*4+rg, col=lc
            float4_ s[4];
            #pragma unroll
            for (int sb = 0; sb < 4; sb++) {
                const bf16x8 kf0 = *(const bf16x8*)(ks + off16[sb][0]);
                const bf16x8 kf1 = *(const bf16x8*)(ks + off16[sb][1]);
                float4_ a = f4zero();
                a = __builtin_amdgcn_mfma_f32_16x16x32_bf16(kf0, qf0, a, 0, 0, 0);
                a = __builtin_amdgcn_mfma_f32_16x16x32_bf16(kf1, qf1, a, 0, 0, 0);
                s[sb] = a;
            }
            if (st >= dstile) {   // causal mask: s_global > t_global
                #pragma unroll
                for (int sb = 0; sb < 4; sb++)
                    #pragma unroll
                    for (int rg = 0; rg < 4; rg++) {
                        const int sg = st * 64 + sb * 16 + quad * 4 + rg;
                        if (sg > tg) s[sb][rg] = -1e30f;
                    }
            }
            // online softmax (exp2 domain), per-lane: 16 scores for q-row tg
            float rm = -1e30f;
            #pragma unroll
            for (int sb = 0; sb < 4; sb++)
                #pragma unroll
                for (int rg = 0; rg < 4; rg++) rm = fmaxf(rm, s[sb][rg]);
            rm = fmaxf(rm, __shfl_xor(rm, 16));
            rm = fmaxf(rm, __shfl_xor(rm, 32));
            // T13 defer-max: skip O/l rescale unless max grew past threshold
            if (!__all(rm <= m_i + 8.f)) {
                const float mn    = fmaxf(m_i, rm);
                const float alpha = __builtin_amdgcn_exp2f(m_i - mn);
                l_i *= alpha;
                #pragma unroll
                for (int db = 0; db < 4; db++)
                    #pragma unroll
                    for (int rg = 0; rg < 4; rg++) o[db][rg] *= alpha;
                m_i = mn;
            }
            float rs = 0.f;
            #pragma unroll
            for (int sb = 0; sb < 4; sb++)
                #pragma unroll
                for (int rg = 0; rg < 4; rg++) {
                    const float p = __builtin_amdgcn_exp2f(s[sb][rg] - m_i);
                    s[sb][rg] = p;
                    rs += p;
                }
            rs += __shfl_xor(rs, 16);
            rs += __shfl_xor(rs, 32);
            l_i += rs;

            // P^T -> LDS as [t][s]; packed pairs via v_cvt_pk_bf16_f32 (T12)
            #pragma unroll
            for (int sb = 0; sb < 4; sb++) {
                uint32x2 pk2;
                pk2[0] = cvtpk(s[sb][0], s[sb][1]);
                pk2[1] = cvtpk(s[sb][2], s[sb][3]);
                *(uint32x2*)(pwr + sb * 32 + quad * 8) = pk2;
            }

            // O^T += V^T P^T: A = Vs row d [k=s], B = Ps row t [k=s]
            const bf16x8 pa0 = *(const bf16x8*)(pwr + quad * 16);
            const bf16x8 pa1 = *(const bf16x8*)(pwr + 64 + quad * 16);
            #pragma unroll
            for (int db = 0; db < 4; db++) {
                const bf16x8 vf0 = *(const bf16x8*)(vs + off16[db][0]);
                const bf16x8 vf1 = *(const bf16x8*)(vs + off16[db][1]);
                o[db] = __builtin_amdgcn_mfma_f32_16x16x32_bf16(vf0, pa0, o[db], 0, 0, 0);
                o[db] = __builtin_amdgcn_mfma_f32_16x16x32_bf16(vf1, pa1, o[db], 0, 0, 0);
            }
        }
        __syncthreads();   // drains vmcnt (prefetch landed) + protects buffers
        cur ^= 1;
    }

    // epilogue: O^T lane owns q-row tg; d = db*16 + quad*4 + rg (4 consecutive)
    const int h = nh & 15;
    const float inv = 1.f / l_i;
    ushort_t* yrow = y_ws + ((size_t)(n * T_ + tg)) * 1024 + h * 64;
    #pragma unroll
    for (int db = 0; db < 4; db++) {
        uint32x2 pk2;
        pk2[0] = cvtpk(o[db][0] * inv, o[db][1] * inv);
        pk2[1] = cvtpk(o[db][2] * inv, o[db][3] * inv);
        *(uint32x2*)(yrow + db * 16 + quad * 4) = pk2;
    }
}

// ---------------------------------------------------------------------------
extern "C" void kernel_launch(void* const* d_in, const int* in_sizes, int n_in,
                              void* d_out, int out_size, void* d_ws, size_t ws_size,
                              hipStream_t stream) {
    (void)in_sizes; (void)n_in; (void)out_size; (void)ws_size;
    const float* x  = (const float*)d_in[0];
    const float* wq = (const float*)d_in[1];
    const float* wk = (const float*)d_in[2];
    const float* wv = (const float*)d_in[3];
    const float* wo = (const float*)d_in[4];
    char* ws = (char*)d_ws;
    const size_t MB = (size_t)1024 * 1024;
    ushort_t* x_bf  = (ushort_t*)(ws);            // 16 MB; reused as y after attn
    ushort_t* q_ws  = (ushort_t*)(ws + 16 * MB);  // 16 MB
    ushort_t* k_ws  = (ushort_t*)(ws + 32 * MB);  // 16 MB
    ushort_t* vt_ws = (ushort_t*)(ws + 48 * MB);  // 16 MB
    ushort_t* wcat  = (ushort_t*)(ws + 64 * MB);  // 6 MB  [3072][1024]
    ushort_t* wot   = (ushort_t*)(ws + 70 * MB);  // 2 MB  [1024(c)][1024(hd)]
    ushort_t* y_ws  = x_bf;                       // safe: attn never reads x_bf
    float*    outp  = (float*)d_out;              // f32 output

    prep_all<<<dim3(11520), dim3(256), 0, stream>>>(x, x_bf, wq, wk, wv, wcat, wo, wot);
    gemm_bt<0><<<dim3(64, 24), dim3(256), 0, stream>>>(x_bf, wcat, q_ws, k_ws, vt_ws, nullptr);
    attn<<<dim3(1024), dim3(512), 0, stream>>>(q_ws, k_ws, vt_ws, y_ws);
    gemm_bt<1><<<dim3(64, 8), dim3(256), 0, stream>>>(y_ws, wot, nullptr, nullptr, nullptr, outp);
}

// Round 9
// 253.408 us; speedup vs baseline: 1.0103x; 1.0103x over previous
//
#include <hip/hip_runtime.h>
#include <stdint.h>

#define B_ 4
#define T_ 2048
#define C_ 1024
#define H_ 16
#define D_ 64
#define M_ (B_*T_)      /* 8192 */
#define K_ C_           /* 1024 */

typedef unsigned short ushort_t;
typedef __bf16 bf16x8 __attribute__((ext_vector_type(8)));
typedef float  float4_ __attribute__((ext_vector_type(4)));
typedef ushort_t ushort4_ __attribute__((ext_vector_type(4)));
typedef uint32_t uint32x2 __attribute__((ext_vector_type(2)));

__device__ __forceinline__ ushort_t f2bf(float f) {
    union { float f; uint32_t u; } c; c.f = f;
    uint32_t u = c.u;
    uint32_t r = (u + 0x7FFFu + ((u >> 16) & 1u)) >> 16;
    return (ushort_t)r;
}
__device__ __forceinline__ float4_ f4zero() { float4_ z; z[0]=0.f; z[1]=0.f; z[2]=0.f; z[3]=0.f; return z; }

// packed f32x2 -> bf16x2 (single HW instr; no builtin on gfx950 — T12 recipe)
__device__ __forceinline__ uint32_t cvtpk(float a, float b) {
    uint32_t r;
    asm("v_cvt_pk_bf16_f32 %0, %1, %2" : "=v"(r) : "v"(a), "v"(b));
    return r;
}

// async global->LDS, 16B per lane; LDS dest must be wave-uniform base + lane*16
#define GLDS16(gptr, lptr) \
    __builtin_amdgcn_global_load_lds((const __attribute__((address_space(1))) uint32_t*)(gptr), \
                                     (__attribute__((address_space(3))) uint32_t*)(lptr), 16, 0, 0)

// ---------------------------------------------------------------------------
// fused input prep (one launch):
//   blocks     0.. 8191:  x f32 [8M elems] -> x_bf bf16
//   blocks  8192..11263:  wq|wk|wv f32 -> wcat bf16 [3072][1024]
//   blocks 11264..11519:  w_o f32 [1024(hd)][1024(c)] -> wot bf16 [1024(c)][1024(hd)]
// ---------------------------------------------------------------------------
__global__ __launch_bounds__(256) void prep_all(const float* __restrict__ x,
                                                ushort_t* __restrict__ x_bf,
                                                const float* __restrict__ s0,
                                                const float* __restrict__ s1,
                                                const float* __restrict__ s2,
                                                ushort_t* __restrict__ dst,
                                                const float* __restrict__ wo,
                                                ushort_t* __restrict__ wot) {
    __shared__ ushort_t tile[64][65];
    const int b = blockIdx.x;
    const int tid = threadIdx.x;
    if (b < 8192) {
        const int i = b * 1024 + tid * 4;
        float4_ v = *(const float4_*)(x + i);
        ushort4_ o;
        #pragma unroll
        for (int e = 0; e < 4; e++) o[e] = f2bf(v[e]);
        *(ushort4_*)(x_bf + i) = o;
    } else if (b < 11264) {
        const int bw = b - 8192;                 // 0..3071
        const float* src = (bw < 1024) ? s0 : (bw < 2048) ? s1 : s2;
        const int off = (bw & 1023) * 1024 + tid * 4;
        float4_ v = *(const float4_*)(src + off);
        ushort4_ o;
        #pragma unroll
        for (int e = 0; e < 4; e++) o[e] = f2bf(v[e]);
        *(ushort4_*)(dst + (size_t)bw * 1024 + tid * 4) = o;
    } else {
        const int bb = b - 11264;                // 0..255
        const int c0 = (bb & 15) * 64;
        const int r0 = (bb >> 4) * 64;           // hd tile base
        const int row = tid >> 2;                // 64 rows, 4 threads/row
        const int col = (tid & 3) * 16;
        #pragma unroll
        for (int r = 0; r < 4; r++) {
            float4_ v = *(const float4_*)(wo + (size_t)(r0 + row) * 1024 + c0 + col + r * 4);
            #pragma unroll
            for (int e = 0; e < 4; e++) tile[row][col + r * 4 + e] = f2bf(v[e]);
        }
        __syncthreads();
        #pragma unroll
        for (int r = 0; r < 2; r++) {
            bf16x8 v;
            #pragma unroll
            for (int e = 0; e < 8; e++) v[e] = __builtin_bit_cast(__bf16, tile[col + r * 8 + e][row]);
            *(bf16x8*)(wot + (size_t)(c0 + row) * 1024 + r0 + col + r * 8) = v;
        }
    }
}

// ---------------------------------------------------------------------------
// GEMM: C[M x N] = A[M x K] * Bt[N x K]^T  (bf16 in, fp32 acc)
// ROUND 9: BK 32 -> 64 on the proven 2-barrier structure. r8's null (FETCH
//   3x up, dur flat) proved the kernel is latency/structure-bound: 32 iters x
//   ~770 cyc (stage + vmcnt(0) drain + 2 barriers + conflicted ds_reads) vs
//   192 cyc MFMA. BK=64 halves the drain/barrier EVENTS (16 iters) while LDS
//   stays 32 KB (single-buffered; avoids m132's 64KB occupancy cliff).
//   128-B rows would be a 16-way ds_read conflict -> r5/r6-verified XOR
//   swizzle (linear glds dest + inverse-swizzled global source + swizzled
//   read; measured 0 conflicts + refcheck'd in both rounds).
//   XCD-chunked swizzle REVERTED (r8: FETCH 49->154 MB, no dur change).
// MODE 0: Bt = Wcat [3072 x 1024]; scatters Q (x 0.125*log2(e), exp2-domain
//         softmax), K [nh][t][d], V^T [nh][d][t] (packed ushort4_ stores)
// MODE 1: Bt = wot [1024 x 1024]; f32 store to d_out
// ---------------------------------------------------------------------------
template<int MODE>
__global__ __launch_bounds__(256)
void gemm_bt(const ushort_t* __restrict__ A,
             const ushort_t* __restrict__ Bt,
             ushort_t* __restrict__ q_ws, ushort_t* __restrict__ k_ws,
             ushort_t* __restrict__ vt_ws, float* __restrict__ outp)
{
    __shared__ __align__(16) ushort_t As[128 * 64];   // 16 KB, swizzled rows
    __shared__ __align__(16) ushort_t Bs[128 * 64];   // 16 KB, swizzled rows
    const int tid = threadIdx.x;
    const int m0 = blockIdx.x * 128;
    const int n0 = blockIdx.y * 128;

    const int L    = tid & 63;
    const int wid  = tid >> 6;
    const int wr   = (wid >> 1) * 64;
    const int wc   = (wid & 1) * 64;
    const int quad = L >> 4;
    const int lc   = L & 15;

    float4_ acc[4][4];
    #pragma unroll
    for (int i = 0; i < 4; i++)
        #pragma unroll
        for (int j = 0; j < 4; j++) acc[i][j] = f4zero();

    // staging: 4 chunks of 4 KB per array (256 thr x 16 B); LDS dest linear,
    // global SOURCE carries the inverse XOR swizzle (rule #21)
    int l_off[4]; size_t a_off[4], b_off[4];
    #pragma unroll
    for (int r = 0; r < 4; r++) {
        const int off = tid * 16 + r * 4096;
        const int row = off >> 7;                        // 0..127
        const int sg  = ((off >> 4) & 7) ^ (row & 7);    // swizzled 16B slot
        l_off[r] = off;
        a_off[r] = (size_t)(m0 + row) * 2048 + sg * 16;
        b_off[r] = (size_t)(n0 + row) * 2048 + sg * 16;
    }
    const char* Ag = (const char*)A;
    const char* Bg = (const char*)Bt;

    // swizzled fragment read offsets; row&7 == lc&7 for all fragment rows
    int offA[4][2], offB[4][2];
    #pragma unroll
    for (int i = 0; i < 4; i++)
        #pragma unroll
        for (int ks = 0; ks < 2; ks++) {
            const int ra = wr + i * 16 + lc;
            const int rb = wc + i * 16 + lc;
            offA[i][ks] = ra * 128 + (((ks * 4 + quad) ^ (lc & 7)) << 4);
            offB[i][ks] = rb * 128 + (((ks * 4 + quad) ^ (lc & 7)) << 4);
        }

    for (int k0 = 0; k0 < K_; k0 += 64) {
        __syncthreads();
        #pragma unroll
        for (int r = 0; r < 4; r++) {
            GLDS16(Ag + a_off[r] + (size_t)k0 * 2, (char*)As + l_off[r]);
            GLDS16(Bg + b_off[r] + (size_t)k0 * 2, (char*)Bs + l_off[r]);
        }
        __syncthreads();
        #pragma unroll
        for (int ks = 0; ks < 2; ks++) {
            bf16x8 af[4], bfr[4];
            #pragma unroll
            for (int i = 0; i < 4; i++) {
                af[i]  = *(const bf16x8*)((const char*)As + offA[i][ks]);
                bfr[i] = *(const bf16x8*)((const char*)Bs + offB[i][ks]);
            }
            #pragma unroll
            for (int i = 0; i < 4; i++)
                #pragma unroll
                for (int j = 0; j < 4; j++)
                    acc[i][j] = __builtin_amdgcn_mfma_f32_16x16x32_bf16(af[i], bfr[j], acc[i][j], 0, 0, 0);
        }
    }

    // epilogue: C/D layout col=lane&15, row=quad*4+reg (m89-verified)
    const int mat = n0 >> 10;          // MODE 0: which of q/k/v
    const int nb  = n0 & 1023;
    if (MODE == 1) {
        #pragma unroll
        for (int i = 0; i < 4; i++)
            #pragma unroll
            for (int j = 0; j < 4; j++)
                #pragma unroll
                for (int rg = 0; rg < 4; rg++) {
                    const int mg = m0 + wr + i * 16 + quad * 4 + rg;
                    const int cg = n0 + wc + j * 16 + lc;
                    outp[(size_t)mg * 1024 + cg] = acc[i][j][rg];     // f32 store
                }
    } else if (mat == 2) {
        // V^T [nh][d][t]: rg values are t-consecutive -> one ushort4_ per (i,j)
        #pragma unroll
        for (int i = 0; i < 4; i++) {
            const int mg0 = m0 + wr + i * 16 + quad * 4;
            const int n = mg0 >> 11, t0 = mg0 & 2047;
            #pragma unroll
            for (int j = 0; j < 4; j++) {
                const int ln = nb + wc + j * 16 + lc;
                const int h = ln >> 6, d = ln & 63;
                const int nh = n * H_ + h;
                ushort4_ pk;
                #pragma unroll
                for (int rg = 0; rg < 4; rg++) pk[rg] = f2bf(acc[i][j][rg]);
                *(ushort4_*)(vt_ws + ((size_t)nh * 64 + d) * T_ + t0) = pk;
            }
        }
    } else {
        // Q (x 0.125*log2(e): softmax computed with exp2) or K, [nh][t][d]
        const float scl = (mat == 0) ? 0.18033688011112042f : 1.0f;
        ushort_t* dstp  = (mat == 0) ? q_ws : k_ws;
        #pragma unroll
        for (int i = 0; i < 4; i++)
            #pragma unroll
            for (int j = 0; j < 4; j++)
                #pragma unroll
                for (int rg = 0; rg < 4; rg++) {
                    const int mg = m0 + wr + i * 16 + quad * 4 + rg;
                    const int ln = nb + wc + j * 16 + lc;
                    const int h = ln >> 6, d = ln & 63;
                    const int n = mg >> 11, t = mg & 2047;
                    const int nh = n * H_ + h;
                    dstp[((size_t)nh * T_ + t) * 64 + d] = f2bf(acc[i][j][rg] * scl);
                }
    }
}

// ---------------------------------------------------------------------------
// MFMA flash attention, transposed formulation (round-3, validated):
//   S^T = K Q^T ; O^T = V^T P^T ; per-lane scalar softmax state (exp2 domain).
//   Global heavy-first dispatch + XCD-local nh mapping.
// ---------------------------------------------------------------------------
#define KP 72   /* Ps padded row pitch, elements (P path only) */

__global__ __launch_bounds__(512)
void attn(const ushort_t* __restrict__ q_ws, const ushort_t* __restrict__ k_ws,
          const ushort_t* __restrict__ vt_ws, ushort_t* __restrict__ y_ws)
{
    __shared__ __align__(16) ushort_t Ks[2][64 * 64];   // [s][d] 128B pitch, swizzled
    __shared__ __align__(16) ushort_t Vs[2][64 * 64];   // [d][s] 128B pitch, swizzled
    __shared__ __align__(16) ushort_t Ps[8][16 * KP];   // per-wave P^T as [t][s]
    const int tid  = threadIdx.x;
    const int L    = tid & 63;
    const int w    = tid >> 6;           // 0..7
    const int quad = L >> 4, lc = L & 15;
    const int bid  = blockIdx.x;
    const int qt   = 15 - (bid >> 6);    // GLOBAL heavy-first: qt=15 blocks first
    const int nh   = bid & 63;           // bid%8 == nh%8 -> XCD-local K/V
    const int n    = nh >> 4;
    const int tq0  = qt * 128 + w * 16;
    const int tg   = tq0 + lc;           // this lane's q-row
    const int nt   = 2 * qt + 2;         // K/V 64-tiles this block touches
    const int dstile = tq0 >> 6;         // first tile needing the causal mask

    // Q fragments (B-operand layout [n=t=lc][k=d=quad*8+j]):
    const ushort_t* qbase = q_ws + ((size_t)nh * T_ + tq0) * 64;
    const bf16x8 qf0 = *(const bf16x8*)(qbase + (size_t)lc * 64 + quad * 8);
    const bf16x8 qf1 = *(const bf16x8*)(qbase + (size_t)lc * 64 + quad * 8 + 32);

    float m_i = -1e30f, l_i = 0.f;       // per-lane scalars (q-row tg), log2 domain
    float4_ o[4];                        // O^T C-layout: col=t (lane), row=d
    #pragma unroll
    for (int r = 0; r < 4; r++) o[r] = f4zero();

    const char* kbase = (const char*)(k_ws  + (size_t)nh * T_ * 64);   // [t][d]
    const char* vbase = (const char*)(vt_ws + (size_t)nh * 64 * T_);   // [d][t]
    char* pwr = (char*)Ps[w] + lc * (KP * 2);

    // staging: 512 threads x 16B = one 8KB tile per glds instruction.
    const int ldsoff = tid * 16;                 // linear byte offset in 8KB buffer
    const int srow   = ldsoff >> 7;              // 0..63
    const int sslot  = (ldsoff >> 4) & 7;
    const int sgs    = sslot ^ (srow & 7);       // inverse swizzle on SOURCE
    const size_t kgo = (size_t)srow * 128 + sgs * 16;
    const size_t vgo = (size_t)srow * (T_ * 2) + sgs * 16;

    // loop-invariant swizzled read offsets (rows b*16+lc, 16B slots quad/quad+4)
    int off16[4][2];
    #pragma unroll
    for (int b = 0; b < 4; b++) {
        const int row = b * 16 + lc;
        const int r7  = lc & 7;                  // (b*16+lc)&7 == lc&7
        off16[b][0] = row * 128 + ((quad ^ r7) << 4);
        off16[b][1] = row * 128 + (((quad + 4) ^ r7) << 4);
    }

    auto STAGE = [&](int st, int b) {
        GLDS16(kbase + (size_t)st * 8192 + kgo, (char*)Ks[b] + ldsoff);
        GLDS16(vbase + (size_t)st * 128  + vgo, (char*)Vs[b] + ldsoff);
    };

    STAGE(0, 0);
    __syncthreads();                      // drains vmcnt(0): buf0 staged
    int cur = 0;

    for (int st = 0; st < nt; st++) {
        if (st + 1 < nt) STAGE(st + 1, cur ^ 1);   // prefetch overlaps compute
        // wave-uniform skip of fully-masked final tile (lower-half waves)
        if (st * 64 <= tq0 + 15) {
            const char* ks = (const char*)Ks[cur];
            const char* vs = (const char*)Vs[cur];

            // S^T = K Q^T: 4 s-blocks of 16; D[s][t]: row=quad*4+rg, col=lc
            float4_ s[4];
            #pragma unroll
            for (int sb = 0; sb < 4; sb++) {
                const bf16x8 kf0 = *(const bf16x8*)(ks + off16[sb][0]);
                const bf16x8 kf1 = *(const bf16x8*)(ks + off16[sb][1]);
                float4_ a = f4zero();
                a = __builtin_amdgcn_mfma_f32_16x16x32_bf16(kf0, qf0, a, 0, 0, 0);
                a = __builtin_amdgcn_mfma_f32_16x16x32_bf16(kf1, qf1, a, 0, 0, 0);
                s[sb] = a;
            }
            if (st >= dstile) {   // causal mask: s_global > t_global
                #pragma unroll
                for (int sb = 0; sb < 4; sb++)
                    #pragma unroll
                    for (int rg = 0; rg < 4; rg++) {
                        const int sg = st * 64 + sb * 16 + quad * 4 + rg;
                        if (sg > tg) s[sb][rg] = -1e30f;
                    }
            }
            // online softmax (exp2 domain), per-lane: 16 scores for q-row tg
            float rm = -1e30f;
            #pragma unroll
            for (int sb = 0; sb < 4; sb++)
                #pragma unroll
                for (int rg = 0; rg < 4; rg++) rm = fmaxf(rm, s[sb][rg]);
            rm = fmaxf(rm, __shfl_xor(rm, 16));
            rm = fmaxf(rm, __shfl_xor(rm, 32));
            // T13 defer-max: skip O/l rescale unless max grew past threshold
            if (!__all(rm <= m_i + 8.f)) {
                const float mn    = fmaxf(m_i, rm);
                const float alpha = __builtin_amdgcn_exp2f(m_i - mn);
                l_i *= alpha;
                #pragma unroll
                for (int db = 0; db < 4; db++)
                    #pragma unroll
                    for (int rg = 0; rg < 4; rg++) o[db][rg] *= alpha;
                m_i = mn;
            }
            float rs = 0.f;
            #pragma unroll
            for (int sb = 0; sb < 4; sb++)
                #pragma unroll
                for (int rg = 0; rg < 4; rg++) {
                    const float p = __builtin_amdgcn_exp2f(s[sb][rg] - m_i);
                    s[sb][rg] = p;
                    rs += p;
                }
            rs += __shfl_xor(rs, 16);
            rs += __shfl_xor(rs, 32);
            l_i += rs;

            // P^T -> LDS as [t][s]; packed pairs via v_cvt_pk_bf16_f32 (T12)
            #pragma unroll
            for (int sb = 0; sb < 4; sb++) {
                uint32x2 pk2;
                pk2[0] = cvtpk(s[sb][0], s[sb][1]);
                pk2[1] = cvtpk(s[sb][2], s[sb][3]);
                *(uint32x2*)(pwr + sb * 32 + quad * 8) = pk2;
            }

            // O^T += V^T P^T: A = Vs row d [k=s], B = Ps row t [k=s]
            const bf16x8 pa0 = *(const bf16x8*)(pwr + quad * 16);
            const bf16x8 pa1 = *(const bf16x8*)(pwr + 64 + quad * 16);
            #pragma unroll
            for (int db = 0; db < 4; db++) {
                const bf16x8 vf0 = *(const bf16x8*)(vs + off16[db][0]);
                const bf16x8 vf1 = *(const bf16x8*)(vs + off16[db][1]);
                o[db] = __builtin_amdgcn_mfma_f32_16x16x32_bf16(vf0, pa0, o[db], 0, 0, 0);
                o[db] = __builtin_amdgcn_mfma_f32_16x16x32_bf16(vf1, pa1, o[db], 0, 0, 0);
            }
        }
        __syncthreads();   // drains vmcnt (prefetch landed) + protects buffers
        cur ^= 1;
    }

    // epilogue: O^T lane owns q-row tg; d = db*16 + quad*4 + rg (4 consecutive)
    const int h = nh & 15;
    const float inv = 1.f / l_i;
    ushort_t* yrow = y_ws + ((size_t)(n * T_ + tg)) * 1024 + h * 64;
    #pragma unroll
    for (int db = 0; db < 4; db++) {
        uint32x2 pk2;
        pk2[0] = cvtpk(o[db][0] * inv, o[db][1] * inv);
        pk2[1] = cvtpk(o[db][2] * inv, o[db][3] * inv);
        *(uint32x2*)(yrow + db * 16 + quad * 4) = pk2;
    }
}

// ---------------------------------------------------------------------------
extern "C" void kernel_launch(void* const* d_in, const int* in_sizes, int n_in,
                              void* d_out, int out_size, void* d_ws, size_t ws_size,
                              hipStream_t stream) {
    (void)in_sizes; (void)n_in; (void)out_size; (void)ws_size;
    const float* x  = (const float*)d_in[0];
    const float* wq = (const float*)d_in[1];
    const float* wk = (const float*)d_in[2];
    const float* wv = (const float*)d_in[3];
    const float* wo = (const float*)d_in[4];
    char* ws = (char*)d_ws;
    const size_t MB = (size_t)1024 * 1024;
    ushort_t* x_bf  = (ushort_t*)(ws);            // 16 MB; reused as y after attn
    ushort_t* q_ws  = (ushort_t*)(ws + 16 * MB);  // 16 MB
    ushort_t* k_ws  = (ushort_t*)(ws + 32 * MB);  // 16 MB
    ushort_t* vt_ws = (ushort_t*)(ws + 48 * MB);  // 16 MB
    ushort_t* wcat  = (ushort_t*)(ws + 64 * MB);  // 6 MB  [3072][1024]
    ushort_t* wot   = (ushort_t*)(ws + 70 * MB);  // 2 MB  [1024(c)][1024(hd)]
    ushort_t* y_ws  = x_bf;                       // safe: attn never reads x_bf
    float*    outp  = (float*)d_out;              // f32 output

    prep_all<<<dim3(11520), dim3(256), 0, stream>>>(x, x_bf, wq, wk, wv, wcat, wo, wot);
    gemm_bt<0><<<dim3(64, 24), dim3(256), 0, stream>>>(x_bf, wcat, q_ws, k_ws, vt_ws, nullptr);
    attn<<<dim3(1024), dim3(512), 0, stream>>>(q_ws, k_ws, vt_ws, y_ws);
    gemm_bt<1><<<dim3(64, 8), dim3(256), 0, stream>>>(y_ws, wot, nullptr, nullptr, nullptr, outp);
}

// Round 10
// 251.056 us; speedup vs baseline: 1.0198x; 1.0094x over previous
//
#include <hip/hip_runtime.h>
#include <stdint.h>

#define B_ 4
#define T_ 2048
#define C_ 1024
#define H_ 16
#define D_ 64
#define M_ (B_*T_)      /* 8192 */
#define K_ C_           /* 1024 */

typedef unsigned short ushort_t;
typedef __bf16 bf16x8 __attribute__((ext_vector_type(8)));
typedef float  float4_ __attribute__((ext_vector_type(4)));
typedef ushort_t ushort4_ __attribute__((ext_vector_type(4)));
typedef uint32_t uint32x2 __attribute__((ext_vector_type(2)));

__device__ __forceinline__ ushort_t f2bf(float f) {
    union { float f; uint32_t u; } c; c.f = f;
    uint32_t u = c.u;
    uint32_t r = (u + 0x7FFFu + ((u >> 16) & 1u)) >> 16;
    return (ushort_t)r;
}
__device__ __forceinline__ float4_ f4zero() { float4_ z; z[0]=0.f; z[1]=0.f; z[2]=0.f; z[3]=0.f; return z; }

// packed f32x2 -> bf16x2 (single HW instr; no builtin on gfx950 — T12 recipe)
__device__ __forceinline__ uint32_t cvtpk(float a, float b) {
    uint32_t r;
    asm("v_cvt_pk_bf16_f32 %0, %1, %2" : "=v"(r) : "v"(a), "v"(b));
    return r;
}

// async global->LDS, 16B per lane; LDS dest must be wave-uniform base + lane*16
#define GLDS16(gptr, lptr) \
    __builtin_amdgcn_global_load_lds((const __attribute__((address_space(1))) uint32_t*)(gptr), \
                                     (__attribute__((address_space(3))) uint32_t*)(lptr), 16, 0, 0)

// ---------------------------------------------------------------------------
// fused input prep (one launch):
//   blocks     0.. 8191:  x f32 [8M elems] -> x_bf bf16
//   blocks  8192..11263:  wq|wk|wv f32 -> wcat bf16 [3072][1024]
//   blocks 11264..11519:  w_o f32 [1024(hd)][1024(c)] -> wot bf16 [1024(c)][1024(hd)]
// ---------------------------------------------------------------------------
__global__ __launch_bounds__(256) void prep_all(const float* __restrict__ x,
                                                ushort_t* __restrict__ x_bf,
                                                const float* __restrict__ s0,
                                                const float* __restrict__ s1,
                                                const float* __restrict__ s2,
                                                ushort_t* __restrict__ dst,
                                                const float* __restrict__ wo,
                                                ushort_t* __restrict__ wot) {
    __shared__ ushort_t tile[64][65];
    const int b = blockIdx.x;
    const int tid = threadIdx.x;
    if (b < 8192) {
        const int i = b * 1024 + tid * 4;
        float4_ v = *(const float4_*)(x + i);
        ushort4_ o;
        #pragma unroll
        for (int e = 0; e < 4; e++) o[e] = f2bf(v[e]);
        *(ushort4_*)(x_bf + i) = o;
    } else if (b < 11264) {
        const int bw = b - 8192;                 // 0..3071
        const float* src = (bw < 1024) ? s0 : (bw < 2048) ? s1 : s2;
        const int off = (bw & 1023) * 1024 + tid * 4;
        float4_ v = *(const float4_*)(src + off);
        ushort4_ o;
        #pragma unroll
        for (int e = 0; e < 4; e++) o[e] = f2bf(v[e]);
        *(ushort4_*)(dst + (size_t)bw * 1024 + tid * 4) = o;
    } else {
        const int bb = b - 11264;                // 0..255
        const int c0 = (bb & 15) * 64;
        const int r0 = (bb >> 4) * 64;           // hd tile base
        const int row = tid >> 2;                // 64 rows, 4 threads/row
        const int col = (tid & 3) * 16;
        #pragma unroll
        for (int r = 0; r < 4; r++) {
            float4_ v = *(const float4_*)(wo + (size_t)(r0 + row) * 1024 + c0 + col + r * 4);
            #pragma unroll
            for (int e = 0; e < 4; e++) tile[row][col + r * 4 + e] = f2bf(v[e]);
        }
        __syncthreads();
        #pragma unroll
        for (int r = 0; r < 2; r++) {
            bf16x8 v;
            #pragma unroll
            for (int e = 0; e < 8; e++) v[e] = __builtin_bit_cast(__bf16, tile[col + r * 8 + e][row]);
            *(bf16x8*)(wot + (size_t)(c0 + row) * 1024 + r0 + col + r * 8) = v;
        }
    }
}

// ---------------------------------------------------------------------------
// GEMM: C[M x N] = A[M x K] * Bt[N x K]^T  (bf16 in, fp32 acc)
// r9-validated: BK=64, 2-barrier loop, glds width=16, XOR-swizzled LDS
// (SQ_LDS_BANK_CONFLICT = 0 measured). 683 TF = the 2-phase structural
// ceiling (matches m230-V0's 682); deep-pipeline ports regressed 3x — parked.
// MODE 0: Bt = Wcat [3072 x 1024]; scatters Q (x 0.125*log2(e), exp2-domain
//         softmax), K [nh][t][d], V^T [nh][d][t] (packed ushort4_ stores)
// MODE 1: Bt = wot [1024 x 1024]; f32 store to d_out
// ---------------------------------------------------------------------------
template<int MODE>
__global__ __launch_bounds__(256)
void gemm_bt(const ushort_t* __restrict__ A,
             const ushort_t* __restrict__ Bt,
             ushort_t* __restrict__ q_ws, ushort_t* __restrict__ k_ws,
             ushort_t* __restrict__ vt_ws, float* __restrict__ outp)
{
    __shared__ __align__(16) ushort_t As[128 * 64];   // 16 KB, swizzled rows
    __shared__ __align__(16) ushort_t Bs[128 * 64];   // 16 KB, swizzled rows
    const int tid = threadIdx.x;
    const int m0 = blockIdx.x * 128;
    const int n0 = blockIdx.y * 128;

    const int L    = tid & 63;
    const int wid  = tid >> 6;
    const int wr   = (wid >> 1) * 64;
    const int wc   = (wid & 1) * 64;
    const int quad = L >> 4;
    const int lc   = L & 15;

    float4_ acc[4][4];
    #pragma unroll
    for (int i = 0; i < 4; i++)
        #pragma unroll
        for (int j = 0; j < 4; j++) acc[i][j] = f4zero();

    // staging: 4 chunks of 4 KB per array (256 thr x 16 B); LDS dest linear,
    // global SOURCE carries the inverse XOR swizzle (rule #21)
    int l_off[4]; size_t a_off[4], b_off[4];
    #pragma unroll
    for (int r = 0; r < 4; r++) {
        const int off = tid * 16 + r * 4096;
        const int row = off >> 7;                        // 0..127
        const int sg  = ((off >> 4) & 7) ^ (row & 7);    // swizzled 16B slot
        l_off[r] = off;
        a_off[r] = (size_t)(m0 + row) * 2048 + sg * 16;
        b_off[r] = (size_t)(n0 + row) * 2048 + sg * 16;
    }
    const char* Ag = (const char*)A;
    const char* Bg = (const char*)Bt;

    // swizzled fragment read offsets; row&7 == lc&7 for all fragment rows
    int offA[4][2], offB[4][2];
    #pragma unroll
    for (int i = 0; i < 4; i++)
        #pragma unroll
        for (int ks = 0; ks < 2; ks++) {
            const int ra = wr + i * 16 + lc;
            const int rb = wc + i * 16 + lc;
            offA[i][ks] = ra * 128 + (((ks * 4 + quad) ^ (lc & 7)) << 4);
            offB[i][ks] = rb * 128 + (((ks * 4 + quad) ^ (lc & 7)) << 4);
        }

    for (int k0 = 0; k0 < K_; k0 += 64) {
        __syncthreads();
        #pragma unroll
        for (int r = 0; r < 4; r++) {
            GLDS16(Ag + a_off[r] + (size_t)k0 * 2, (char*)As + l_off[r]);
            GLDS16(Bg + b_off[r] + (size_t)k0 * 2, (char*)Bs + l_off[r]);
        }
        __syncthreads();
        #pragma unroll
        for (int ks = 0; ks < 2; ks++) {
            bf16x8 af[4], bfr[4];
            #pragma unroll
            for (int i = 0; i < 4; i++) {
                af[i]  = *(const bf16x8*)((const char*)As + offA[i][ks]);
                bfr[i] = *(const bf16x8*)((const char*)Bs + offB[i][ks]);
            }
            #pragma unroll
            for (int i = 0; i < 4; i++)
                #pragma unroll
                for (int j = 0; j < 4; j++)
                    acc[i][j] = __builtin_amdgcn_mfma_f32_16x16x32_bf16(af[i], bfr[j], acc[i][j], 0, 0, 0);
        }
    }

    // epilogue: C/D layout col=lane&15, row=quad*4+reg (m89-verified)
    const int mat = n0 >> 10;          // MODE 0: which of q/k/v
    const int nb  = n0 & 1023;
    if (MODE == 1) {
        #pragma unroll
        for (int i = 0; i < 4; i++)
            #pragma unroll
            for (int j = 0; j < 4; j++)
                #pragma unroll
                for (int rg = 0; rg < 4; rg++) {
                    const int mg = m0 + wr + i * 16 + quad * 4 + rg;
                    const int cg = n0 + wc + j * 16 + lc;
                    outp[(size_t)mg * 1024 + cg] = acc[i][j][rg];     // f32 store
                }
    } else if (mat == 2) {
        // V^T [nh][d][t]: rg values are t-consecutive -> one ushort4_ per (i,j)
        #pragma unroll
        for (int i = 0; i < 4; i++) {
            const int mg0 = m0 + wr + i * 16 + quad * 4;
            const int n = mg0 >> 11, t0 = mg0 & 2047;
            #pragma unroll
            for (int j = 0; j < 4; j++) {
                const int ln = nb + wc + j * 16 + lc;
                const int h = ln >> 6, d = ln & 63;
                const int nh = n * H_ + h;
                ushort4_ pk;
                #pragma unroll
                for (int rg = 0; rg < 4; rg++) pk[rg] = f2bf(acc[i][j][rg]);
                *(ushort4_*)(vt_ws + ((size_t)nh * 64 + d) * T_ + t0) = pk;
            }
        }
    } else {
        // Q (x 0.125*log2(e): softmax computed with exp2) or K, [nh][t][d]
        const float scl = (mat == 0) ? 0.18033688011112042f : 1.0f;
        ushort_t* dstp  = (mat == 0) ? q_ws : k_ws;
        #pragma unroll
        for (int i = 0; i < 4; i++)
            #pragma unroll
            for (int j = 0; j < 4; j++)
                #pragma unroll
                for (int rg = 0; rg < 4; rg++) {
                    const int mg = m0 + wr + i * 16 + quad * 4 + rg;
                    const int ln = nb + wc + j * 16 + lc;
                    const int h = ln >> 6, d = ln & 63;
                    const int n = mg >> 11, t = mg & 2047;
                    const int nh = n * H_ + h;
                    dstp[((size_t)nh * T_ + t) * 64 + d] = f2bf(acc[i][j][rg] * scl);
                }
    }
}

// ---------------------------------------------------------------------------
// MFMA flash attention, transposed formulation:
//   S^T = K Q^T ; O^T = V^T P^T ; per-lane scalar softmax state (exp2 domain).
// ROUND 10: QBLK 128 -> 256 (16 waves, 1024 threads).
//   Same per-wave math/swizzles/softmax as the r3-validated kernel; each
//   staged K/V tile now serves 256 q-rows: block-iters 17408 -> 9216
//   (staging + barrier events ~halved), K/V HBM re-reads halved.
//   LDS = 32 KB K/V dbuf + 36 KB Ps = 68 KB -> 2 blocks/CU x 16 waves =
//   32 waves/CU (max, was 24). Grid 512 = exactly 2/CU -> single round,
//   all blocks resident from t=0. Staging split: waves 0-7 stage K,
//   waves 8-15 stage V (wave-uniform branch; glds base+lane*16 preserved).
//   + T5 setprio around MFMA clusters (attn-proven +4-7%, m191)
//   + tree-shaped max reduction (shorter serial fmax chain).
// ---------------------------------------------------------------------------
#define KP 72   /* Ps padded row pitch, elements (P path only) */

__global__ __launch_bounds__(1024)
void attn(const ushort_t* __restrict__ q_ws, const ushort_t* __restrict__ k_ws,
          const ushort_t* __restrict__ vt_ws, ushort_t* __restrict__ y_ws)
{
    __shared__ __align__(16) ushort_t Ks[2][64 * 64];   // [s][d] 128B pitch, swizzled
    __shared__ __align__(16) ushort_t Vs[2][64 * 64];   // [d][s] 128B pitch, swizzled
    __shared__ __align__(16) ushort_t Ps[16][16 * KP];  // per-wave P^T as [t][s]
    const int tid  = threadIdx.x;
    const int L    = tid & 63;
    const int w    = tid >> 6;           // 0..15
    const int quad = L >> 4, lc = L & 15;
    const int bid  = blockIdx.x;
    const int qt   = 7 - (bid >> 6);     // heavy-first: qt=7 blocks are bids 0..63
    const int nh   = bid & 63;           // bid%8 == nh%8 -> XCD-local K/V
    const int n    = nh >> 4;
    const int tq0  = qt * 256 + w * 16;
    const int tg   = tq0 + lc;           // this lane's q-row
    const int nt   = 4 * qt + 4;         // K/V 64-tiles this block touches
    const int dstile = tq0 >> 6;         // first tile needing the causal mask

    // Q fragments (B-operand layout [n=t=lc][k=d=quad*8+j]):
    const ushort_t* qbase = q_ws + ((size_t)nh * T_ + tq0) * 64;
    const bf16x8 qf0 = *(const bf16x8*)(qbase + (size_t)lc * 64 + quad * 8);
    const bf16x8 qf1 = *(const bf16x8*)(qbase + (size_t)lc * 64 + quad * 8 + 32);

    float m_i = -1e30f, l_i = 0.f;       // per-lane scalars (q-row tg), log2 domain
    float4_ o[4];                        // O^T C-layout: col=t (lane), row=d
    #pragma unroll
    for (int r = 0; r < 4; r++) o[r] = f4zero();

    const char* kbase = (const char*)(k_ws  + (size_t)nh * T_ * 64);   // [t][d]
    const char* vbase = (const char*)(vt_ws + (size_t)nh * 64 * T_);   // [d][t]
    char* pwr = (char*)Ps[w] + lc * (KP * 2);

    // staging: waves 0-7 stage K, waves 8-15 stage V; 512 thr x 16B = 8KB tile
    // per glds. LDS dest linear; global SOURCE carries the inverse XOR swizzle.
    const int sid    = tid & 511;
    const int ldsoff = sid * 16;                 // linear byte offset in 8KB buffer
    const int srow   = ldsoff >> 7;              // 0..63
    const int sslot  = (ldsoff >> 4) & 7;
    const int sgs    = sslot ^ (srow & 7);       // inverse swizzle on SOURCE
    const size_t kgo = (size_t)srow * 128 + sgs * 16;
    const size_t vgo = (size_t)srow * (T_ * 2) + sgs * 16;

    // loop-invariant swizzled read offsets (rows b*16+lc, 16B slots quad/quad+4)
    int off16[4][2];
    #pragma unroll
    for (int b = 0; b < 4; b++) {
        const int row = b * 16 + lc;
        const int r7  = lc & 7;                  // (b*16+lc)&7 == lc&7
        off16[b][0] = row * 128 + ((quad ^ r7) << 4);
        off16[b][1] = row * 128 + (((quad + 4) ^ r7) << 4);
    }

    auto STAGE = [&](int st, int b) {
        if (w < 8) GLDS16(kbase + (size_t)st * 8192 + kgo, (char*)Ks[b] + ldsoff);
        else       GLDS16(vbase + (size_t)st * 128  + vgo, (char*)Vs[b] + ldsoff);
    };

    STAGE(0, 0);
    __syncthreads();                      // drains vmcnt(0): buf0 staged
    int cur = 0;

    for (int st = 0; st < nt; st++) {
        if (st + 1 < nt) STAGE(st + 1, cur ^ 1);   // prefetch overlaps compute
        // wave-uniform skip of fully-masked tiles (lower waves near diagonal)
        if (st * 64 <= tq0 + 15) {
            const char* ks = (const char*)Ks[cur];
            const char* vs = (const char*)Vs[cur];

            // S^T = K Q^T: 4 s-blocks of 16; D[s][t]: row=quad*4+rg, col=lc
            float4_ s[4];
            __builtin_amdgcn_s_setprio(1);
            #pragma unroll
            for (int sb = 0; sb < 4; sb++) {
                const bf16x8 kf0 = *(const bf16x8*)(ks + off16[sb][0]);
                const bf16x8 kf1 = *(const bf16x8*)(ks + off16[sb][1]);
                float4_ a = f4zero();
                a = __builtin_amdgcn_mfma_f32_16x16x32_bf16(kf0, qf0, a, 0, 0, 0);
                a = __builtin_amdgcn_mfma_f32_16x16x32_bf16(kf1, qf1, a, 0, 0, 0);
                s[sb] = a;
            }
            __builtin_amdgcn_s_setprio(0);
            if (st >= dstile) {   // causal mask: s_global > t_global
                #pragma unroll
                for (int sb = 0; sb < 4; sb++)
                    #pragma unroll
                    for (int rg = 0; rg < 4; rg++) {
                        const int sg = st * 64 + sb * 16 + quad * 4 + rg;
                        if (sg > tg) s[sb][rg] = -1e30f;
                    }
            }
            // online softmax (exp2 domain), per-lane; tree-shaped max
            float tm[4];
            #pragma unroll
            for (int sb = 0; sb < 4; sb++)
                tm[sb] = fmaxf(fmaxf(s[sb][0], s[sb][1]), fmaxf(s[sb][2], s[sb][3]));
            float rm = fmaxf(fmaxf(tm[0], tm[1]), fmaxf(tm[2], tm[3]));
            rm = fmaxf(rm, __shfl_xor(rm, 16));
            rm = fmaxf(rm, __shfl_xor(rm, 32));
            // T13 defer-max: skip O/l rescale unless max grew past threshold
            if (!__all(rm <= m_i + 8.f)) {
                const float mn    = fmaxf(m_i, rm);
                const float alpha = __builtin_amdgcn_exp2f(m_i - mn);
                l_i *= alpha;
                #pragma unroll
                for (int db = 0; db < 4; db++)
                    #pragma unroll
                    for (int rg = 0; rg < 4; rg++) o[db][rg] *= alpha;
                m_i = mn;
            }
            float rs = 0.f;
            #pragma unroll
            for (int sb = 0; sb < 4; sb++)
                #pragma unroll
                for (int rg = 0; rg < 4; rg++) {
                    const float p = __builtin_amdgcn_exp2f(s[sb][rg] - m_i);
                    s[sb][rg] = p;
                    rs += p;
                }
            rs += __shfl_xor(rs, 16);
            rs += __shfl_xor(rs, 32);
            l_i += rs;

            // P^T -> LDS as [t][s]; packed pairs via v_cvt_pk_bf16_f32 (T12)
            #pragma unroll
            for (int sb = 0; sb < 4; sb++) {
                uint32x2 pk2;
                pk2[0] = cvtpk(s[sb][0], s[sb][1]);
                pk2[1] = cvtpk(s[sb][2], s[sb][3]);
                *(uint32x2*)(pwr + sb * 32 + quad * 8) = pk2;
            }

            // O^T += V^T P^T: A = Vs row d [k=s], B = Ps row t [k=s]
            const bf16x8 pa0 = *(const bf16x8*)(pwr + quad * 16);
            const bf16x8 pa1 = *(const bf16x8*)(pwr + 64 + quad * 16);
            __builtin_amdgcn_s_setprio(1);
            #pragma unroll
            for (int db = 0; db < 4; db++) {
                const bf16x8 vf0 = *(const bf16x8*)(vs + off16[db][0]);
                const bf16x8 vf1 = *(const bf16x8*)(vs + off16[db][1]);
                o[db] = __builtin_amdgcn_mfma_f32_16x16x32_bf16(vf0, pa0, o[db], 0, 0, 0);
                o[db] = __builtin_amdgcn_mfma_f32_16x16x32_bf16(vf1, pa1, o[db], 0, 0, 0);
            }
            __builtin_amdgcn_s_setprio(0);
        }
        __syncthreads();   // drains vmcnt (prefetch landed) + protects buffers
        cur ^= 1;
    }

    // epilogue: O^T lane owns q-row tg; d = db*16 + quad*4 + rg (4 consecutive)
    const int h = nh & 15;
    const float inv = 1.f / l_i;
    ushort_t* yrow = y_ws + ((size_t)(n * T_ + tg)) * 1024 + h * 64;
    #pragma unroll
    for (int db = 0; db < 4; db++) {
        uint32x2 pk2;
        pk2[0] = cvtpk(o[db][0] * inv, o[db][1] * inv);
        pk2[1] = cvtpk(o[db][2] * inv, o[db][3] * inv);
        *(uint32x2*)(yrow + db * 16 + quad * 4) = pk2;
    }
}

// ---------------------------------------------------------------------------
extern "C" void kernel_launch(void* const* d_in, const int* in_sizes, int n_in,
                              void* d_out, int out_size, void* d_ws, size_t ws_size,
                              hipStream_t stream) {
    (void)in_sizes; (void)n_in; (void)out_size; (void)ws_size;
    const float* x  = (const float*)d_in[0];
    const float* wq = (const float*)d_in[1];
    const float* wk = (const float*)d_in[2];
    const float* wv = (const float*)d_in[3];
    const float* wo = (const float*)d_in[4];
    char* ws = (char*)d_ws;
    const size_t MB = (size_t)1024 * 1024;
    ushort_t* x_bf  = (ushort_t*)(ws);            // 16 MB; reused as y after attn
    ushort_t* q_ws  = (ushort_t*)(ws + 16 * MB);  // 16 MB
    ushort_t* k_ws  = (ushort_t*)(ws + 32 * MB);  // 16 MB
    ushort_t* vt_ws = (ushort_t*)(ws + 48 * MB);  // 16 MB
    ushort_t* wcat  = (ushort_t*)(ws + 64 * MB);  // 6 MB  [3072][1024]
    ushort_t* wot   = (ushort_t*)(ws + 70 * MB);  // 2 MB  [1024(c)][1024(hd)]
    ushort_t* y_ws  = x_bf;                       // safe: attn never reads x_bf
    float*    outp  = (float*)d_out;              // f32 output

    prep_all<<<dim3(11520), dim3(256), 0, stream>>>(x, x_bf, wq, wk, wv, wcat, wo, wot);
    gemm_bt<0><<<dim3(64, 24), dim3(256), 0, stream>>>(x_bf, wcat, q_ws, k_ws, vt_ws, nullptr);
    attn<<<dim3(512), dim3(1024), 0, stream>>>(q_ws, k_ws, vt_ws, y_ws);
    gemm_bt<1><<<dim3(64, 8), dim3(256), 0, stream>>>(y_ws, wot, nullptr, nullptr, nullptr, outp);
}

// Round 11
// 245.684 us; speedup vs baseline: 1.0421x; 1.0219x over previous
//
#include <hip/hip_runtime.h>
#include <stdint.h>

#define B_ 4
#define T_ 2048
#define C_ 1024
#define H_ 16
#define D_ 64
#define M_ (B_*T_)      /* 8192 */
#define K_ C_           /* 1024 */

typedef unsigned short ushort_t;
typedef __bf16 bf16x8 __attribute__((ext_vector_type(8)));
typedef float  float4_ __attribute__((ext_vector_type(4)));
typedef ushort_t ushort4_ __attribute__((ext_vector_type(4)));
typedef uint32_t uint32x2 __attribute__((ext_vector_type(2)));

__device__ __forceinline__ ushort_t f2bf(float f) {
    union { float f; uint32_t u; } c; c.f = f;
    uint32_t u = c.u;
    uint32_t r = (u + 0x7FFFu + ((u >> 16) & 1u)) >> 16;
    return (ushort_t)r;
}
__device__ __forceinline__ float4_ f4zero() { float4_ z; z[0]=0.f; z[1]=0.f; z[2]=0.f; z[3]=0.f; return z; }

// packed f32x2 -> bf16x2 (single HW instr; no builtin on gfx950 — T12 recipe)
__device__ __forceinline__ uint32_t cvtpk(float a, float b) {
    uint32_t r;
    asm("v_cvt_pk_bf16_f32 %0, %1, %2" : "=v"(r) : "v"(a), "v"(b));
    return r;
}

// async global->LDS, 16B per lane; LDS dest must be wave-uniform base + lane*16
#define GLDS16(gptr, lptr) \
    __builtin_amdgcn_global_load_lds((const __attribute__((address_space(1))) uint32_t*)(gptr), \
                                     (__attribute__((address_space(3))) uint32_t*)(lptr), 16, 0, 0)

// ---------------------------------------------------------------------------
// fused input prep (one launch):
//   blocks     0.. 8191:  x f32 [8M elems] -> x_bf bf16
//   blocks  8192..11263:  wq|wk|wv f32 -> wcat bf16 [3072][1024]
//   blocks 11264..11519:  w_o f32 [1024(hd)][1024(c)] -> wot bf16 [1024(c)][1024(hd)]
// ---------------------------------------------------------------------------
__global__ __launch_bounds__(256) void prep_all(const float* __restrict__ x,
                                                ushort_t* __restrict__ x_bf,
                                                const float* __restrict__ s0,
                                                const float* __restrict__ s1,
                                                const float* __restrict__ s2,
                                                ushort_t* __restrict__ dst,
                                                const float* __restrict__ wo,
                                                ushort_t* __restrict__ wot) {
    __shared__ ushort_t tile[64][65];
    const int b = blockIdx.x;
    const int tid = threadIdx.x;
    if (b < 8192) {
        const int i = b * 1024 + tid * 4;
        float4_ v = *(const float4_*)(x + i);
        ushort4_ o;
        #pragma unroll
        for (int e = 0; e < 4; e++) o[e] = f2bf(v[e]);
        *(ushort4_*)(x_bf + i) = o;
    } else if (b < 11264) {
        const int bw = b - 8192;                 // 0..3071
        const float* src = (bw < 1024) ? s0 : (bw < 2048) ? s1 : s2;
        const int off = (bw & 1023) * 1024 + tid * 4;
        float4_ v = *(const float4_*)(src + off);
        ushort4_ o;
        #pragma unroll
        for (int e = 0; e < 4; e++) o[e] = f2bf(v[e]);
        *(ushort4_*)(dst + (size_t)bw * 1024 + tid * 4) = o;
    } else {
        const int bb = b - 11264;                // 0..255
        const int c0 = (bb & 15) * 64;
        const int r0 = (bb >> 4) * 64;           // hd tile base
        const int row = tid >> 2;                // 64 rows, 4 threads/row
        const int col = (tid & 3) * 16;
        #pragma unroll
        for (int r = 0; r < 4; r++) {
            float4_ v = *(const float4_*)(wo + (size_t)(r0 + row) * 1024 + c0 + col + r * 4);
            #pragma unroll
            for (int e = 0; e < 4; e++) tile[row][col + r * 4 + e] = f2bf(v[e]);
        }
        __syncthreads();
        #pragma unroll
        for (int r = 0; r < 2; r++) {
            bf16x8 v;
            #pragma unroll
            for (int e = 0; e < 8; e++) v[e] = __builtin_bit_cast(__bf16, tile[col + r * 8 + e][row]);
            *(bf16x8*)(wot + (size_t)(c0 + row) * 1024 + r0 + col + r * 8) = v;
        }
    }
}

// ---------------------------------------------------------------------------
// GEMM: C[M x N] = A[M x K] * Bt[N x K]^T  (bf16 in, fp32 acc)
// ROUND 11: double-buffered staging, ONE __syncthreads per K-tile (T3-min,
//   mirrors the attn loop that works). r9's single-buffer put the glds L2
//   latency inside an exposed vmcnt(0) drain (nothing to overlap: this
//   tile's MFMA needs the data, prev tile is done). Now tile t+1's 8 glds
//   issue BEFORE tile t's ds_read+MFMA (~600+ cyc of cover); the barrier's
//   vmcnt(0) then drains already-landed loads.
//   WAR: writes to buf^1 protected by prev iter's barrier. RAW: reads of
//   buf staged last iter covered by that iter's drain.
//   Keeps r9's BK=64 + XOR swizzle (conflicts = 0 measured). LDS 64 KB.
// MODE 0: Bt = Wcat [3072 x 1024]; scatters Q (x 0.125*log2(e), exp2-domain
//         softmax), K [nh][t][d], V^T [nh][d][t] (packed ushort4_ stores)
// MODE 1: Bt = wot [1024 x 1024]; f32 store to d_out
// ---------------------------------------------------------------------------
template<int MODE>
__global__ __launch_bounds__(256)
void gemm_bt(const ushort_t* __restrict__ A,
             const ushort_t* __restrict__ Bt,
             ushort_t* __restrict__ q_ws, ushort_t* __restrict__ k_ws,
             ushort_t* __restrict__ vt_ws, float* __restrict__ outp)
{
    __shared__ __align__(16) ushort_t As2[2][128 * 64];   // 2 x 16 KB, swizzled
    __shared__ __align__(16) ushort_t Bs2[2][128 * 64];   // 2 x 16 KB, swizzled
    const int tid = threadIdx.x;
    const int m0 = blockIdx.x * 128;
    const int n0 = blockIdx.y * 128;

    const int L    = tid & 63;
    const int wid  = tid >> 6;
    const int wr   = (wid >> 1) * 64;
    const int wc   = (wid & 1) * 64;
    const int quad = L >> 4;
    const int lc   = L & 15;

    float4_ acc[4][4];
    #pragma unroll
    for (int i = 0; i < 4; i++)
        #pragma unroll
        for (int j = 0; j < 4; j++) acc[i][j] = f4zero();

    // staging: 4 chunks of 4 KB per array (256 thr x 16 B); LDS dest linear,
    // global SOURCE carries the inverse XOR swizzle (rule #21)
    int l_off[4]; size_t a_off[4], b_off[4];
    #pragma unroll
    for (int r = 0; r < 4; r++) {
        const int off = tid * 16 + r * 4096;
        const int row = off >> 7;                        // 0..127
        const int sg  = ((off >> 4) & 7) ^ (row & 7);    // swizzled 16B slot
        l_off[r] = off;
        a_off[r] = (size_t)(m0 + row) * 2048 + sg * 16;
        b_off[r] = (size_t)(n0 + row) * 2048 + sg * 16;
    }
    const char* Ag = (const char*)A;
    const char* Bg = (const char*)Bt;

    // swizzled fragment read offsets; row&7 == lc&7 for all fragment rows
    int offA[4][2], offB[4][2];
    #pragma unroll
    for (int i = 0; i < 4; i++)
        #pragma unroll
        for (int ks = 0; ks < 2; ks++) {
            const int ra = wr + i * 16 + lc;
            const int rb = wc + i * 16 + lc;
            offA[i][ks] = ra * 128 + (((ks * 4 + quad) ^ (lc & 7)) << 4);
            offB[i][ks] = rb * 128 + (((ks * 4 + quad) ^ (lc & 7)) << 4);
        }

    auto STAGE = [&](int kt, int buf) {
        #pragma unroll
        for (int r = 0; r < 4; r++) {
            GLDS16(Ag + a_off[r] + (size_t)kt * 128, (char*)As2[buf] + l_off[r]);
            GLDS16(Bg + b_off[r] + (size_t)kt * 128, (char*)Bs2[buf] + l_off[r]);
        }
    };

    STAGE(0, 0);
    __syncthreads();                      // drains vmcnt(0): buf0 staged
    int cur = 0;

    for (int kt = 0; kt < 16; kt++) {
        if (kt + 1 < 16) STAGE(kt + 1, cur ^ 1);   // prefetch hides under compute
        const char* as = (const char*)As2[cur];
        const char* bs = (const char*)Bs2[cur];
        #pragma unroll
        for (int ks = 0; ks < 2; ks++) {
            bf16x8 af[4], bfr[4];
            #pragma unroll
            for (int i = 0; i < 4; i++) {
                af[i]  = *(const bf16x8*)(as + offA[i][ks]);
                bfr[i] = *(const bf16x8*)(bs + offB[i][ks]);
            }
            #pragma unroll
            for (int i = 0; i < 4; i++)
                #pragma unroll
                for (int j = 0; j < 4; j++)
                    acc[i][j] = __builtin_amdgcn_mfma_f32_16x16x32_bf16(af[i], bfr[j], acc[i][j], 0, 0, 0);
        }
        __syncthreads();   // drains vmcnt (prefetch landed) + protects buffers
        cur ^= 1;
    }

    // epilogue: C/D layout col=lane&15, row=quad*4+reg (m89-verified)
    const int mat = n0 >> 10;          // MODE 0: which of q/k/v
    const int nb  = n0 & 1023;
    if (MODE == 1) {
        #pragma unroll
        for (int i = 0; i < 4; i++)
            #pragma unroll
            for (int j = 0; j < 4; j++)
                #pragma unroll
                for (int rg = 0; rg < 4; rg++) {
                    const int mg = m0 + wr + i * 16 + quad * 4 + rg;
                    const int cg = n0 + wc + j * 16 + lc;
                    outp[(size_t)mg * 1024 + cg] = acc[i][j][rg];     // f32 store
                }
    } else if (mat == 2) {
        // V^T [nh][d][t]: rg values are t-consecutive -> one ushort4_ per (i,j)
        #pragma unroll
        for (int i = 0; i < 4; i++) {
            const int mg0 = m0 + wr + i * 16 + quad * 4;
            const int n = mg0 >> 11, t0 = mg0 & 2047;
            #pragma unroll
            for (int j = 0; j < 4; j++) {
                const int ln = nb + wc + j * 16 + lc;
                const int h = ln >> 6, d = ln & 63;
                const int nh = n * H_ + h;
                ushort4_ pk;
                #pragma unroll
                for (int rg = 0; rg < 4; rg++) pk[rg] = f2bf(acc[i][j][rg]);
                *(ushort4_*)(vt_ws + ((size_t)nh * 64 + d) * T_ + t0) = pk;
            }
        }
    } else {
        // Q (x 0.125*log2(e): softmax computed with exp2) or K, [nh][t][d]
        const float scl = (mat == 0) ? 0.18033688011112042f : 1.0f;
        ushort_t* dstp  = (mat == 0) ? q_ws : k_ws;
        #pragma unroll
        for (int i = 0; i < 4; i++)
            #pragma unroll
            for (int j = 0; j < 4; j++)
                #pragma unroll
                for (int rg = 0; rg < 4; rg++) {
                    const int mg = m0 + wr + i * 16 + quad * 4 + rg;
                    const int ln = nb + wc + j * 16 + lc;
                    const int h = ln >> 6, d = ln & 63;
                    const int n = mg >> 11, t = mg & 2047;
                    const int nh = n * H_ + h;
                    dstp[((size_t)nh * T_ + t) * 64 + d] = f2bf(acc[i][j][rg] * scl);
                }
    }
}

// ---------------------------------------------------------------------------
// MFMA flash attention, transposed formulation (r10-validated):
//   S^T = K Q^T ; O^T = V^T P^T ; per-lane scalar softmax state (exp2 domain).
//   QBLK=256 (16 waves), heavy-first dispatch, XCD-local nh, K/V staging
//   split across wave halves, T5 setprio, tree max.
// ---------------------------------------------------------------------------
#define KP 72   /* Ps padded row pitch, elements (P path only) */

__global__ __launch_bounds__(1024)
void attn(const ushort_t* __restrict__ q_ws, const ushort_t* __restrict__ k_ws,
          const ushort_t* __restrict__ vt_ws, ushort_t* __restrict__ y_ws)
{
    __shared__ __align__(16) ushort_t Ks[2][64 * 64];   // [s][d] 128B pitch, swizzled
    __shared__ __align__(16) ushort_t Vs[2][64 * 64];   // [d][s] 128B pitch, swizzled
    __shared__ __align__(16) ushort_t Ps[16][16 * KP];  // per-wave P^T as [t][s]
    const int tid  = threadIdx.x;
    const int L    = tid & 63;
    const int w    = tid >> 6;           // 0..15
    const int quad = L >> 4, lc = L & 15;
    const int bid  = blockIdx.x;
    const int qt   = 7 - (bid >> 6);     // heavy-first: qt=7 blocks are bids 0..63
    const int nh   = bid & 63;           // bid%8 == nh%8 -> XCD-local K/V
    const int n    = nh >> 4;
    const int tq0  = qt * 256 + w * 16;
    const int tg   = tq0 + lc;           // this lane's q-row
    const int nt   = 4 * qt + 4;         // K/V 64-tiles this block touches
    const int dstile = tq0 >> 6;         // first tile needing the causal mask

    // Q fragments (B-operand layout [n=t=lc][k=d=quad*8+j]):
    const ushort_t* qbase = q_ws + ((size_t)nh * T_ + tq0) * 64;
    const bf16x8 qf0 = *(const bf16x8*)(qbase + (size_t)lc * 64 + quad * 8);
    const bf16x8 qf1 = *(const bf16x8*)(qbase + (size_t)lc * 64 + quad * 8 + 32);

    float m_i = -1e30f, l_i = 0.f;       // per-lane scalars (q-row tg), log2 domain
    float4_ o[4];                        // O^T C-layout: col=t (lane), row=d
    #pragma unroll
    for (int r = 0; r < 4; r++) o[r] = f4zero();

    const char* kbase = (const char*)(k_ws  + (size_t)nh * T_ * 64);   // [t][d]
    const char* vbase = (const char*)(vt_ws + (size_t)nh * 64 * T_);   // [d][t]
    char* pwr = (char*)Ps[w] + lc * (KP * 2);

    // staging: waves 0-7 stage K, waves 8-15 stage V; 512 thr x 16B = 8KB tile
    // per glds. LDS dest linear; global SOURCE carries the inverse XOR swizzle.
    const int sid    = tid & 511;
    const int ldsoff = sid * 16;                 // linear byte offset in 8KB buffer
    const int srow   = ldsoff >> 7;              // 0..63
    const int sslot  = (ldsoff >> 4) & 7;
    const int sgs    = sslot ^ (srow & 7);       // inverse swizzle on SOURCE
    const size_t kgo = (size_t)srow * 128 + sgs * 16;
    const size_t vgo = (size_t)srow * (T_ * 2) + sgs * 16;

    // loop-invariant swizzled read offsets (rows b*16+lc, 16B slots quad/quad+4)
    int off16[4][2];
    #pragma unroll
    for (int b = 0; b < 4; b++) {
        const int row = b * 16 + lc;
        const int r7  = lc & 7;                  // (b*16+lc)&7 == lc&7
        off16[b][0] = row * 128 + ((quad ^ r7) << 4);
        off16[b][1] = row * 128 + (((quad + 4) ^ r7) << 4);
    }

    auto STAGE = [&](int st, int b) {
        if (w < 8) GLDS16(kbase + (size_t)st * 8192 + kgo, (char*)Ks[b] + ldsoff);
        else       GLDS16(vbase + (size_t)st * 128  + vgo, (char*)Vs[b] + ldsoff);
    };

    STAGE(0, 0);
    __syncthreads();                      // drains vmcnt(0): buf0 staged
    int cur = 0;

    for (int st = 0; st < nt; st++) {
        if (st + 1 < nt) STAGE(st + 1, cur ^ 1);   // prefetch overlaps compute
        // wave-uniform skip of fully-masked tiles (lower waves near diagonal)
        if (st * 64 <= tq0 + 15) {
            const char* ks = (const char*)Ks[cur];
            const char* vs = (const char*)Vs[cur];

            // S^T = K Q^T: 4 s-blocks of 16; D[s][t]: row=quad*4+rg, col=lc
            float4_ s[4];
            __builtin_amdgcn_s_setprio(1);
            #pragma unroll
            for (int sb = 0; sb < 4; sb++) {
                const bf16x8 kf0 = *(const bf16x8*)(ks + off16[sb][0]);
                const bf16x8 kf1 = *(const bf16x8*)(ks + off16[sb][1]);
                float4_ a = f4zero();
                a = __builtin_amdgcn_mfma_f32_16x16x32_bf16(kf0, qf0, a, 0, 0, 0);
                a = __builtin_amdgcn_mfma_f32_16x16x32_bf16(kf1, qf1, a, 0, 0, 0);
                s[sb] = a;
            }
            __builtin_amdgcn_s_setprio(0);
            if (st >= dstile) {   // causal mask: s_global > t_global
                #pragma unroll
                for (int sb = 0; sb < 4; sb++)
                    #pragma unroll
                    for (int rg = 0; rg < 4; rg++) {
                        const int sg = st * 64 + sb * 16 + quad * 4 + rg;
                        if (sg > tg) s[sb][rg] = -1e30f;
                    }
            }
            // online softmax (exp2 domain), per-lane; tree-shaped max
            float tm[4];
            #pragma unroll
            for (int sb = 0; sb < 4; sb++)
                tm[sb] = fmaxf(fmaxf(s[sb][0], s[sb][1]), fmaxf(s[sb][2], s[sb][3]));
            float rm = fmaxf(fmaxf(tm[0], tm[1]), fmaxf(tm[2], tm[3]));
            rm = fmaxf(rm, __shfl_xor(rm, 16));
            rm = fmaxf(rm, __shfl_xor(rm, 32));
            // T13 defer-max: skip O/l rescale unless max grew past threshold
            if (!__all(rm <= m_i + 8.f)) {
                const float mn    = fmaxf(m_i, rm);
                const float alpha = __builtin_amdgcn_exp2f(m_i - mn);
                l_i *= alpha;
                #pragma unroll
                for (int db = 0; db < 4; db++)
                    #pragma unroll
                    for (int rg = 0; rg < 4; rg++) o[db][rg] *= alpha;
                m_i = mn;
            }
            float rs = 0.f;
            #pragma unroll
            for (int sb = 0; sb < 4; sb++)
                #pragma unroll
                for (int rg = 0; rg < 4; rg++) {
                    const float p = __builtin_amdgcn_exp2f(s[sb][rg] - m_i);
                    s[sb][rg] = p;
                    rs += p;
                }
            rs += __shfl_xor(rs, 16);
            rs += __shfl_xor(rs, 32);
            l_i += rs;

            // P^T -> LDS as [t][s]; packed pairs via v_cvt_pk_bf16_f32 (T12)
            #pragma unroll
            for (int sb = 0; sb < 4; sb++) {
                uint32x2 pk2;
                pk2[0] = cvtpk(s[sb][0], s[sb][1]);
                pk2[1] = cvtpk(s[sb][2], s[sb][3]);
                *(uint32x2*)(pwr + sb * 32 + quad * 8) = pk2;
            }

            // O^T += V^T P^T: A = Vs row d [k=s], B = Ps row t [k=s]
            const bf16x8 pa0 = *(const bf16x8*)(pwr + quad * 16);
            const bf16x8 pa1 = *(const bf16x8*)(pwr + 64 + quad * 16);
            __builtin_amdgcn_s_setprio(1);
            #pragma unroll
            for (int db = 0; db < 4; db++) {
                const bf16x8 vf0 = *(const bf16x8*)(vs + off16[db][0]);
                const bf16x8 vf1 = *(const bf16x8*)(vs + off16[db][1]);
                o[db] = __builtin_amdgcn_mfma_f32_16x16x32_bf16(vf0, pa0, o[db], 0, 0, 0);
                o[db] = __builtin_amdgcn_mfma_f32_16x16x32_bf16(vf1, pa1, o[db], 0, 0, 0);
            }
            __builtin_amdgcn_s_setprio(0);
        }
        __syncthreads();   // drains vmcnt (prefetch landed) + protects buffers
        cur ^= 1;
    }

    // epilogue: O^T lane owns q-row tg; d = db*16 + quad*4 + rg (4 consecutive)
    const int h = nh & 15;
    const float inv = 1.f / l_i;
    ushort_t* yrow = y_ws + ((size_t)(n * T_ + tg)) * 1024 + h * 64;
    #pragma unroll
    for (int db = 0; db < 4; db++) {
        uint32x2 pk2;
        pk2[0] = cvtpk(o[db][0] * inv, o[db][1] * inv);
        pk2[1] = cvtpk(o[db][2] * inv, o[db][3] * inv);
        *(uint32x2*)(yrow + db * 16 + quad * 4) = pk2;
    }
}

// ---------------------------------------------------------------------------
extern "C" void kernel_launch(void* const* d_in, const int* in_sizes, int n_in,
                              void* d_out, int out_size, void* d_ws, size_t ws_size,
                              hipStream_t stream) {
    (void)in_sizes; (void)n_in; (void)out_size; (void)ws_size;
    const float* x  = (const float*)d_in[0];
    const float* wq = (const float*)d_in[1];
    const float* wk = (const float*)d_in[2];
    const float* wv = (const float*)d_in[3];
    const float* wo = (const float*)d_in[4];
    char* ws = (char*)d_ws;
    const size_t MB = (size_t)1024 * 1024;
    ushort_t* x_bf  = (ushort_t*)(ws);            // 16 MB; reused as y after attn
    ushort_t* q_ws  = (ushort_t*)(ws + 16 * MB);  // 16 MB
    ushort_t* k_ws  = (ushort_t*)(ws + 32 * MB);  // 16 MB
    ushort_t* vt_ws = (ushort_t*)(ws + 48 * MB);  // 16 MB
    ushort_t* wcat  = (ushort_t*)(ws + 64 * MB);  // 6 MB  [3072][1024]
    ushort_t* wot   = (ushort_t*)(ws + 70 * MB);  // 2 MB  [1024(c)][1024(hd)]
    ushort_t* y_ws  = x_bf;                       // safe: attn never reads x_bf
    float*    outp  = (float*)d_out;              // f32 output

    prep_all<<<dim3(11520), dim3(256), 0, stream>>>(x, x_bf, wq, wk, wv, wcat, wo, wot);
    gemm_bt<0><<<dim3(64, 24), dim3(256), 0, stream>>>(x_bf, wcat, q_ws, k_ws, vt_ws, nullptr);
    attn<<<dim3(512), dim3(1024), 0, stream>>>(q_ws, k_ws, vt_ws, y_ws);
    gemm_bt<1><<<dim3(64, 8), dim3(256), 0, stream>>>(y_ws, wot, nullptr, nullptr, nullptr, outp);
}